// Round 10
// baseline (114.877 us; speedup 1.0000x reference)
//
#include <hip/hip_runtime.h>
#include <hip/hip_fp16.h>

// DifferentiableRGBtoVel: image (4,3,512,512) fp32, cmap (256,3) fp32, v_i (256) fp32
// out velocities (4,512,512) fp32.
//
// v13 (barrier-free main loop, wave-private staging; math identical to v11/v12,
// absmax 0.00390625): logit'_k = 14 - K2*|c_k - p|^2 in exp2 units.
//   MFMA #1 bf16 (3-way splits, 24-slot scheme) -> logits; lane l holds 4
//   logits of pixel (l&15); exp2 -> v_cvt_pkrtz f16; MFMA #2 f16 vs Bv
//   (col0=1, col1=v_k permuted) accumulates s and s*v on the matrix pipe.
// v12 post-mortem: persistent blocks were NEUTRAL (42.4us, VALUBusy down to 53%)
// -> the ~15-20us idle is NOT per-block ramp; it is barrier lockstep: 2
// __syncthreads per generation force all 8 waves to re-converge every ~2500cy,
// draining the trans/MFMA pipes while staging/epilogue of the slowest wave
// completes. v13: pixel staging LDS is WAVE-PRIVATE (lanes 0-31 load+split the
// wave's own 32 pixels into the wave's own 2560B slice; consumers are the same
// wave) -> in-wave DS ordering + lgkmcnt replace __syncthreads; zero barriers
// after the table prologue; waves free-run and desynchronize, keeping the
// transcendental pipe fed. Next-gen loads issue before the u-loop (HBM latency
// hidden under compute); stage-writes land after.

typedef __attribute__((ext_vector_type(8))) short short8;     // 8 bf16
typedef __attribute__((ext_vector_type(8))) _Float16 f16x8;   // 8 f16
typedef __attribute__((ext_vector_type(4))) float f32x4;

#define HWSZ 262144              // 512*512
#define NPIX 1048576             // 4*512*512
#define K2F  144.2695040888963f  // 1/(0.01*ln2)
#define BIASF 14.0f              // logit bias (cancels in ratio)
#define PXB  256                 // pixels per tile-generation (block-wide)
#define GRID 512                 // persistent blocks (2/CU)
#define GENS 8                   // GRID*GENS*PXB == NPIX

// round f32 -> bf16 bits (RNE); residual (exact in fp32) returned via *resid
static __device__ __forceinline__ unsigned f2bf(float x, float* resid) {
  unsigned u = __builtin_bit_cast(unsigned, x);
  unsigned r = (u + 0x7fffu + ((u >> 16) & 1u)) >> 16;
  if (resid) *resid = x - __builtin_bit_cast(float, r << 16);
  return r;
}
static __device__ __forceinline__ unsigned bfp(unsigned lo, unsigned hi) {
  return (lo & 0xffffu) | (hi << 16);
}
// pack two f32 -> one dword of two RTZ f16 (v_cvt_pkrtz_f16_f32)
static __device__ __forceinline__ unsigned pkrtz(float a, float b) {
  return __builtin_bit_cast(unsigned, __builtin_amdgcn_cvt_pkrtz(a, b));
}

// 3-way-split a pixel and write its 4 B-frag rows (80B stride) to sb[0..3].
static __device__ __forceinline__ void stage_px(float p0, float p1, float p2,
                                                int4* sb) {
  float pc[3] = {p0, p1, p2};
  unsigned ph[3], pm[3], pl[3];
  float r;
#pragma unroll
  for (int ch = 0; ch < 3; ++ch) {
    ph[ch] = f2bf(pc[ch], &r);
    pm[ch] = f2bf(r, &r);
    pl[ch] = f2bf(r, nullptr);
  }
  float qv = K2F * (p0 * p0 + p1 * p1 + p2 * p2);
  unsigned qh = f2bf(qv, &r);
  unsigned qm = f2bf(r, &r);
  unsigned ql = f2bf(r, nullptr);
  const unsigned ONE = 0x3F80u;
  sb[0] = make_int4((int)bfp(ph[0], ph[1]), (int)bfp(ph[2], pm[0]),
                    (int)bfp(pm[1], pm[2]), (int)bfp(ph[0], ph[1]));
  sb[1] = make_int4((int)bfp(ph[2], ph[0]), (int)bfp(ph[1], ph[2]),
                    (int)bfp(pm[0], pm[1]), (int)bfp(pm[2], pl[0]));
  sb[2] = make_int4((int)bfp(pl[1], pl[2]), (int)bfp(ONE, ONE),
                    (int)bfp(ONE, qh),      (int)bfp(qm, ql));
  sb[3] = make_int4(0, 0, 0, 0);
}

__global__ __launch_bounds__(512, 4) void rgb2vel_main(
    const float* __restrict__ img, const float* __restrict__ cmap,
    const float* __restrict__ vv, float* __restrict__ out) {
  // wave-private pixel slices: wave w owns sA4[w*32*5 .. +160)
  __shared__ __align__(16) int4 sA4[8 * 32 * 5];  // 20K, 80B per pixel
  __shared__ __align__(16) int4 sB4[1024];        // color A-frag table: 16K
  __shared__ __align__(16) int4 sBv4[512];        // reduction Bv table: 8K
  const int tid = threadIdx.x;
  const int lane = tid & 63;
  const int warp = tid >> 6;   // 0..7
  const int c = lane & 15;     // pixel-in-tile (D1 col / D2 row-group owner)
  const int g = lane >> 4;     // k-chunk index
  const int bid = blockIdx.x;

  // ================= table prologue (the only barrier) =================
  if (tid < 256) {
    int k = tid;
    float c0 = cmap[k * 3 + 0], c1 = cmap[k * 3 + 1], c2 = cmap[k * 3 + 2];
    float cc[3] = {c0, c1, c2};
    unsigned H[3], M[3], L[3];
    float r;
#pragma unroll
    for (int ch = 0; ch < 3; ++ch) {          // 3-way split of 2K2*c
      float x = 2.0f * K2F * cc[ch];
      H[ch] = f2bf(x, &r);
      M[ch] = f2bf(r, &r);
      L[ch] = f2bf(r, nullptr);
    }
    float mcc = BIASF - K2F * (c0 * c0 + c1 * c1 + c2 * c2);
    unsigned mh = f2bf(mcc, &r);
    unsigned mm = f2bf(r, &r);
    unsigned ml = f2bf(r, nullptr);
    const unsigned N1 = 0xBF80u;  // -1.0 bf16
    unsigned d[16];
    d[0] = bfp(H[0], H[1]); d[1] = bfp(H[2], H[0]); d[2] = bfp(H[1], H[2]);
    d[3] = bfp(M[0], M[1]); d[4] = bfp(M[2], L[0]); d[5] = bfp(L[1], L[2]);
    d[6] = bfp(M[0], M[1]); d[7] = bfp(M[2], H[0]); d[8] = bfp(H[1], H[2]);
    d[9] = bfp(mh, mm);     d[10] = bfp(ml, N1);    d[11] = bfp(N1, N1);
    d[12] = d[13] = d[14] = d[15] = 0u;
    int col = k & 15, tt = k >> 4;
#pragma unroll
    for (int g2 = 0; g2 < 4; ++g2)
      sB4[tt * 64 + g2 * 16 + col] =
          make_int4((int)d[4 * g2 + 0], (int)d[4 * g2 + 1],
                    (int)d[4 * g2 + 2], (int)d[4 * g2 + 3]);
  }
  {
    int u = tid >> 6, l = tid & 63, cc2 = l & 15, gg = l >> 4;
    int4 q = make_int4(0, 0, 0, 0);
    if (cc2 == 0) {
      q = make_int4(0x3C003C00, 0x3C003C00, 0x3C003C00, 0x3C003C00);  // 1.0h x8
    } else if (cc2 == 1) {
      unsigned hq[4];
#pragma unroll
      for (int jp = 0; jp < 4; ++jp) {
        int j0 = 2 * jp, j1 = 2 * jp + 1;
        int i0 = (2 * u + (j0 >> 2)) * 16 + gg * 4 + (j0 & 3);
        int i1 = (2 * u + (j1 >> 2)) * 16 + gg * 4 + (j1 & 3);
        unsigned h0 = (unsigned)__half_as_ushort(__float2half(vv[i0]));  // RNE
        unsigned h1 = (unsigned)__half_as_ushort(__float2half(vv[i1]));
        hq[jp] = h0 | (h1 << 16);
      }
      q = make_int4((int)hq[0], (int)hq[1], (int)hq[2], (int)hq[3]);
    }
    sBv4[tid] = q;
  }
  __syncthreads();  // tables ready; no further barriers

  // ================= wave-private gen-0 staging =================
  // lane p<32 owns pixel: p<16 -> tile A px p; p>=16 -> tile B px (p-16)
  int4* myslice = &sA4[warp * 32 * 5];
  {
    if (lane < 32) {
      int pofs = (lane < 16) ? (warp * 16 + lane) : (128 + warp * 16 + lane - 16);
      int idx = bid * PXB + pofs;
      int n = idx >> 18;
      int hw = idx & (HWSZ - 1);
      const float* pbp = img + (size_t)n * 3 * HWSZ + hw;
      stage_px(pbp[0], pbp[HWSZ], pbp[2 * HWSZ], &myslice[lane * 5]);
    }
  }

  // ================= barrier-free generation loop =================
  float np0 = 0.f, np1 = 0.f, np2 = 0.f;
  const f32x4 z = {0.f, 0.f, 0.f, 0.f};
#pragma unroll 1
  for (int gen = 0; gen < GENS; ++gen) {
    // this wave's pixel B-frags (in-wave lgkmcnt orders vs the stage writes)
    short8 pfr0 = __builtin_bit_cast(short8, myslice[c * 5 + g]);
    short8 pfr1 = __builtin_bit_cast(short8, myslice[(16 + c) * 5 + g]);

    // issue next-generation pixel loads; latency hides under the u-loop
    if (lane < 32 && gen + 1 < GENS) {
      int pofs = (lane < 16) ? (warp * 16 + lane) : (128 + warp * 16 + lane - 16);
      int idx = (bid + GRID * (gen + 1)) * PXB + pofs;
      int n = idx >> 18;
      int hw = idx & (HWSZ - 1);
      const float* pbp = img + (size_t)n * 3 * HWSZ + hw;
      np0 = pbp[0];
      np1 = pbp[HWSZ];
      np2 = pbp[2 * HWSZ];
    }

    f32x4 accA = z, accB = z;
#pragma unroll
    for (int u = 0; u < 8; ++u) {
      short8 ca = __builtin_bit_cast(short8, sB4[(2 * u) * 64 + lane]);
      short8 cb = __builtin_bit_cast(short8, sB4[(2 * u + 1) * 64 + lane]);
      f32x4 d0a = __builtin_amdgcn_mfma_f32_16x16x32_bf16(ca, pfr0, z, 0, 0, 0);
      f32x4 d1a = __builtin_amdgcn_mfma_f32_16x16x32_bf16(cb, pfr0, z, 0, 0, 0);
      f32x4 d0b = __builtin_amdgcn_mfma_f32_16x16x32_bf16(ca, pfr1, z, 0, 0, 0);
      f32x4 d1b = __builtin_amdgcn_mfma_f32_16x16x32_bf16(cb, pfr1, z, 0, 0, 0);
      union { unsigned w[4]; f16x8 v8; } wa, wb;
      wa.w[0] = pkrtz(__builtin_amdgcn_exp2f(d0a[0]), __builtin_amdgcn_exp2f(d0a[1]));
      wa.w[1] = pkrtz(__builtin_amdgcn_exp2f(d0a[2]), __builtin_amdgcn_exp2f(d0a[3]));
      wa.w[2] = pkrtz(__builtin_amdgcn_exp2f(d1a[0]), __builtin_amdgcn_exp2f(d1a[1]));
      wa.w[3] = pkrtz(__builtin_amdgcn_exp2f(d1a[2]), __builtin_amdgcn_exp2f(d1a[3]));
      wb.w[0] = pkrtz(__builtin_amdgcn_exp2f(d0b[0]), __builtin_amdgcn_exp2f(d0b[1]));
      wb.w[1] = pkrtz(__builtin_amdgcn_exp2f(d0b[2]), __builtin_amdgcn_exp2f(d0b[3]));
      wb.w[2] = pkrtz(__builtin_amdgcn_exp2f(d1b[0]), __builtin_amdgcn_exp2f(d1b[1]));
      wb.w[3] = pkrtz(__builtin_amdgcn_exp2f(d1b[2]), __builtin_amdgcn_exp2f(d1b[3]));
      f16x8 bv = __builtin_bit_cast(f16x8, sBv4[u * 64 + lane]);
      accA = __builtin_amdgcn_mfma_f32_16x16x32_f16(wa.v8, bv, accA, 0, 0, 0);
      accB = __builtin_amdgcn_mfma_f32_16x16x32_f16(wb.v8, bv, accB, 0, 0, 0);
    }

    // stage next generation into our own slice (reads of this gen are done:
    // their data fed the MFMAs above; in-wave DS ordering makes this safe)
    if (lane < 32 && gen + 1 < GENS)
      stage_px(np0, np1, np2, &myslice[lane * 5]);

    // epilogue: lane 16g+0 holds s, lane 16g+1 holds s*v for rows g*4+rr
    float a0 = __shfl_xor(accA[0], 1);
    float a1 = __shfl_xor(accA[1], 1);
    float a2 = __shfl_xor(accA[2], 1);
    float a3 = __shfl_xor(accA[3], 1);
    float b0 = __shfl_xor(accB[0], 1);
    float b1 = __shfl_xor(accB[1], 1);
    float b2 = __shfl_xor(accB[2], 1);
    float b3 = __shfl_xor(accB[3], 1);
    if (c == 0) {
      int pb0 = (bid + GRID * gen) * PXB;
      float* oA = out + pb0 + warp * 16 + g * 4;
      oA[0] = a0 * __builtin_amdgcn_rcpf(accA[0]);
      oA[1] = a1 * __builtin_amdgcn_rcpf(accA[1]);
      oA[2] = a2 * __builtin_amdgcn_rcpf(accA[2]);
      oA[3] = a3 * __builtin_amdgcn_rcpf(accA[3]);
      float* oB = out + pb0 + 128 + warp * 16 + g * 4;
      oB[0] = b0 * __builtin_amdgcn_rcpf(accB[0]);
      oB[1] = b1 * __builtin_amdgcn_rcpf(accB[1]);
      oB[2] = b2 * __builtin_amdgcn_rcpf(accB[2]);
      oB[3] = b3 * __builtin_amdgcn_rcpf(accB[3]);
    }
  }
}

extern "C" void kernel_launch(void* const* d_in, const int* in_sizes, int n_in,
                              void* d_out, int out_size, void* d_ws, size_t ws_size,
                              hipStream_t stream) {
  const float* image = (const float*)d_in[0];  // (4,3,512,512)
  const float* cmap  = (const float*)d_in[1];  // (256,3)
  const float* v_i   = (const float*)d_in[2];  // (256,)
  float* out = (float*)d_out;                  // (4,512,512)

  rgb2vel_main<<<GRID, 512, 0, stream>>>(image, cmap, v_i, out);
}

// Round 11
// 95.741 us; speedup vs baseline: 1.1999x; 1.1999x over previous
//
#include <hip/hip_runtime.h>
#include <hip/hip_fp16.h>

// DifferentiableRGBtoVel: image (4,3,512,512) fp32, cmap (256,3) fp32, v_i (256) fp32
// out velocities (4,512,512) fp32.
//
// v14 == v11 restored (best measured: 41.5us kernel, absmax 0.00390625).
// logit'_k = 14 - K2*|c_k - p|^2 in exp2 units (bias cancels in softmax ratio).
// Dual-MFMA path (verified since v8b):
//   MFMA #1 bf16 (3-way splits, 24-slot scheme) -> logits; lane l holds 4
//   logits of pixel (l&15); exp2 -> v_cvt_pkrtz f16; MFMA #2 f16 vs Bv
//   (col0=1, col1=v_k permuted) accumulates s and s*v on the matrix pipe.
//   80B sA stride (conflict-free, v8b/v11-measured); rcp epilogue.
//
// Structural search log (all refuted, reverted):
//   v12 persistent blocks: NEUTRAL (42.4us) -> idle is not per-block ramp.
//   v13 barrier-free wave-private staging: REGRESSION (62us, FETCH 75MB,
//       WRITE 40MB, VGPR 64 -> spill/locality blowup) -> idle is not barrier
//       lockstep.
// Model: busy 26.3us == 268M v_exp_f32 @ ~16cy/wave64 issue floor (+pkrtz);
// residual ~15us idle is scheduler-inherent to the MFMA->exp->pkrtz->MFMA
// dependency mix (insensitive to occupancy 48-68%, persistence, barriers).

typedef __attribute__((ext_vector_type(8))) short short8;     // 8 bf16
typedef __attribute__((ext_vector_type(8))) _Float16 f16x8;   // 8 f16
typedef __attribute__((ext_vector_type(4))) float f32x4;

#define HWSZ 262144              // 512*512
#define NPIX 1048576             // 4*512*512
#define K2F  144.2695040888963f  // 1/(0.01*ln2)
#define BIASF 14.0f              // logit bias (cancels in ratio)
#define PXB  256                 // pixels per block

// round f32 -> bf16 bits (RNE); residual (exact in fp32) returned via *resid
static __device__ __forceinline__ unsigned f2bf(float x, float* resid) {
  unsigned u = __builtin_bit_cast(unsigned, x);
  unsigned r = (u + 0x7fffu + ((u >> 16) & 1u)) >> 16;
  if (resid) *resid = x - __builtin_bit_cast(float, r << 16);
  return r;
}
static __device__ __forceinline__ unsigned bfp(unsigned lo, unsigned hi) {
  return (lo & 0xffffu) | (hi << 16);
}
// pack two f32 -> one dword of two RTZ f16 (v_cvt_pkrtz_f16_f32)
static __device__ __forceinline__ unsigned pkrtz(float a, float b) {
  return __builtin_bit_cast(unsigned, __builtin_amdgcn_cvt_pkrtz(a, b));
}

__global__ __launch_bounds__(512, 8) void rgb2vel_main(
    const float* __restrict__ img, const float* __restrict__ cmap,
    const float* __restrict__ vv, float* __restrict__ out) {
  __shared__ __align__(16) int4 sA4[PXB * 5];  // pixel B-frag rows, 80B stride: 20K
  __shared__ __align__(16) int4 sB4[1024];     // color A-frag table: 16K
  __shared__ __align__(16) int4 sBv4[512];     // reduction Bv table: 8K
  const int tid = threadIdx.x;
  const int lane = tid & 63;
  const int warp = tid >> 6;   // 0..7
  const int c = lane & 15;     // pixel-in-tile (D1 col / D2 row-group owner)
  const int g = lane >> 4;     // k-chunk index
  const int pb0 = blockIdx.x * PXB;

  if (tid < 256) {
    // ---- color A-frag table (one color per thread) ----
    int k = tid;
    float c0 = cmap[k * 3 + 0], c1 = cmap[k * 3 + 1], c2 = cmap[k * 3 + 2];
    float cc[3] = {c0, c1, c2};
    unsigned H[3], M[3], L[3];
    float r;
#pragma unroll
    for (int ch = 0; ch < 3; ++ch) {          // 3-way split of 2K2*c
      float x = 2.0f * K2F * cc[ch];
      H[ch] = f2bf(x, &r);
      M[ch] = f2bf(r, &r);
      L[ch] = f2bf(r, nullptr);
    }
    float mcc = BIASF - K2F * (c0 * c0 + c1 * c1 + c2 * c2);
    unsigned mh = f2bf(mcc, &r);
    unsigned mm = f2bf(r, &r);
    unsigned ml = f2bf(r, nullptr);
    const unsigned N1 = 0xBF80u;  // -1.0 bf16
    unsigned d[16];
    d[0] = bfp(H[0], H[1]); d[1] = bfp(H[2], H[0]); d[2] = bfp(H[1], H[2]);
    d[3] = bfp(M[0], M[1]); d[4] = bfp(M[2], L[0]); d[5] = bfp(L[1], L[2]);
    d[6] = bfp(M[0], M[1]); d[7] = bfp(M[2], H[0]); d[8] = bfp(H[1], H[2]);
    d[9] = bfp(mh, mm);     d[10] = bfp(ml, N1);    d[11] = bfp(N1, N1);
    d[12] = d[13] = d[14] = d[15] = 0u;
    int col = k & 15, tt = k >> 4;
#pragma unroll
    for (int g2 = 0; g2 < 4; ++g2)
      sB4[tt * 64 + g2 * 16 + col] =
          make_int4((int)d[4 * g2 + 0], (int)d[4 * g2 + 1],
                    (int)d[4 * g2 + 2], (int)d[4 * g2 + 3]);
  } else {
    // ---- stage 256 pixels as B-frag rows (threads 256..511) ----
    int px = tid - 256;
    int idx = pb0 + px;
    int n = idx >> 18;              // HWSZ = 2^18
    int hw = idx & (HWSZ - 1);
    const float* pbp = img + (size_t)n * 3 * HWSZ + hw;
    float p0 = pbp[0], p1 = pbp[HWSZ], p2 = pbp[2 * HWSZ];
    float pc[3] = {p0, p1, p2};
    unsigned ph[3], pm[3], pl[3];
    float r;
#pragma unroll
    for (int ch = 0; ch < 3; ++ch) {  // 3-way split of p
      ph[ch] = f2bf(pc[ch], &r);
      pm[ch] = f2bf(r, &r);
      pl[ch] = f2bf(r, nullptr);
    }
    float qv = K2F * (p0 * p0 + p1 * p1 + p2 * p2);
    unsigned qh = f2bf(qv, &r);
    unsigned qm = f2bf(r, &r);
    unsigned ql = f2bf(r, nullptr);
    const unsigned ONE = 0x3F80u;
    int4* sb = &sA4[px * 5];
    sb[0] = make_int4((int)bfp(ph[0], ph[1]), (int)bfp(ph[2], pm[0]),
                      (int)bfp(pm[1], pm[2]), (int)bfp(ph[0], ph[1]));
    sb[1] = make_int4((int)bfp(ph[2], ph[0]), (int)bfp(ph[1], ph[2]),
                      (int)bfp(pm[0], pm[1]), (int)bfp(pm[2], pl[0]));
    sb[2] = make_int4((int)bfp(pl[1], pl[2]), (int)bfp(ONE, ONE),
                      (int)bfp(ONE, qh),      (int)bfp(qm, ql));
    sb[3] = make_int4(0, 0, 0, 0);
    // sb[4] is pad, never read
  }

  // ---- reduction Bv table (all 512 threads, one 16B entry each) ----
  {
    int u = tid >> 6, l = tid & 63, cc2 = l & 15, gg = l >> 4;
    int4 q = make_int4(0, 0, 0, 0);
    if (cc2 == 0) {
      q = make_int4(0x3C003C00, 0x3C003C00, 0x3C003C00, 0x3C003C00);  // 1.0h x8
    } else if (cc2 == 1) {
      unsigned hq[4];
#pragma unroll
      for (int jp = 0; jp < 4; ++jp) {
        int j0 = 2 * jp, j1 = 2 * jp + 1;
        int i0 = (2 * u + (j0 >> 2)) * 16 + gg * 4 + (j0 & 3);
        int i1 = (2 * u + (j1 >> 2)) * 16 + gg * 4 + (j1 & 3);
        unsigned h0 = (unsigned)__half_as_ushort(__float2half(vv[i0]));  // RNE
        unsigned h1 = (unsigned)__half_as_ushort(__float2half(vv[i1]));
        hq[jp] = h0 | (h1 << 16);
      }
      q = make_int4((int)hq[0], (int)hq[1], (int)hq[2], (int)hq[3]);
    }
    sBv4[tid] = q;
  }
  __syncthreads();

  // two pixel B-frags per wave: tiles at px warp*16 and 128+warp*16
  short8 pfr0 = __builtin_bit_cast(short8, sA4[(warp * 16 + c) * 5 + g]);
  short8 pfr1 = __builtin_bit_cast(short8, sA4[(128 + warp * 16 + c) * 5 + g]);

  f32x4 accA = {0.f, 0.f, 0.f, 0.f};
  f32x4 accB = {0.f, 0.f, 0.f, 0.f};
  const f32x4 z = {0.f, 0.f, 0.f, 0.f};

#pragma unroll
  for (int u = 0; u < 8; ++u) {
    short8 ca = __builtin_bit_cast(short8, sB4[(2 * u) * 64 + lane]);
    short8 cb = __builtin_bit_cast(short8, sB4[(2 * u + 1) * 64 + lane]);
    f32x4 d0a = __builtin_amdgcn_mfma_f32_16x16x32_bf16(ca, pfr0, z, 0, 0, 0);
    f32x4 d1a = __builtin_amdgcn_mfma_f32_16x16x32_bf16(cb, pfr0, z, 0, 0, 0);
    f32x4 d0b = __builtin_amdgcn_mfma_f32_16x16x32_bf16(ca, pfr1, z, 0, 0, 0);
    f32x4 d1b = __builtin_amdgcn_mfma_f32_16x16x32_bf16(cb, pfr1, z, 0, 0, 0);
    union { unsigned w[4]; f16x8 v8; } wa, wb;
    wa.w[0] = pkrtz(__builtin_amdgcn_exp2f(d0a[0]), __builtin_amdgcn_exp2f(d0a[1]));
    wa.w[1] = pkrtz(__builtin_amdgcn_exp2f(d0a[2]), __builtin_amdgcn_exp2f(d0a[3]));
    wa.w[2] = pkrtz(__builtin_amdgcn_exp2f(d1a[0]), __builtin_amdgcn_exp2f(d1a[1]));
    wa.w[3] = pkrtz(__builtin_amdgcn_exp2f(d1a[2]), __builtin_amdgcn_exp2f(d1a[3]));
    wb.w[0] = pkrtz(__builtin_amdgcn_exp2f(d0b[0]), __builtin_amdgcn_exp2f(d0b[1]));
    wb.w[1] = pkrtz(__builtin_amdgcn_exp2f(d0b[2]), __builtin_amdgcn_exp2f(d0b[3]));
    wb.w[2] = pkrtz(__builtin_amdgcn_exp2f(d1b[0]), __builtin_amdgcn_exp2f(d1b[1]));
    wb.w[3] = pkrtz(__builtin_amdgcn_exp2f(d1b[2]), __builtin_amdgcn_exp2f(d1b[3]));
    f16x8 bv = __builtin_bit_cast(f16x8, sBv4[u * 64 + lane]);
    accA = __builtin_amdgcn_mfma_f32_16x16x32_f16(wa.v8, bv, accA, 0, 0, 0);
    accB = __builtin_amdgcn_mfma_f32_16x16x32_f16(wb.v8, bv, accB, 0, 0, 0);
  }

  // lane 16g+0 holds s, lane 16g+1 holds s*v for pixel rows g*4+rr (both tiles)
  float a0 = __shfl_xor(accA[0], 1);
  float a1 = __shfl_xor(accA[1], 1);
  float a2 = __shfl_xor(accA[2], 1);
  float a3 = __shfl_xor(accA[3], 1);
  float b0 = __shfl_xor(accB[0], 1);
  float b1 = __shfl_xor(accB[1], 1);
  float b2 = __shfl_xor(accB[2], 1);
  float b3 = __shfl_xor(accB[3], 1);
  if (c == 0) {
    float* oA = out + pb0 + warp * 16 + g * 4;
    oA[0] = a0 * __builtin_amdgcn_rcpf(accA[0]);
    oA[1] = a1 * __builtin_amdgcn_rcpf(accA[1]);
    oA[2] = a2 * __builtin_amdgcn_rcpf(accA[2]);
    oA[3] = a3 * __builtin_amdgcn_rcpf(accA[3]);
    float* oB = out + pb0 + 128 + warp * 16 + g * 4;
    oB[0] = b0 * __builtin_amdgcn_rcpf(accB[0]);
    oB[1] = b1 * __builtin_amdgcn_rcpf(accB[1]);
    oB[2] = b2 * __builtin_amdgcn_rcpf(accB[2]);
    oB[3] = b3 * __builtin_amdgcn_rcpf(accB[3]);
  }
}

extern "C" void kernel_launch(void* const* d_in, const int* in_sizes, int n_in,
                              void* d_out, int out_size, void* d_ws, size_t ws_size,
                              hipStream_t stream) {
  const float* image = (const float*)d_in[0];  // (4,3,512,512)
  const float* cmap  = (const float*)d_in[1];  // (256,3)
  const float* v_i   = (const float*)d_in[2];  // (256,)
  float* out = (float*)d_out;                  // (4,512,512)

  rgb2vel_main<<<NPIX / PXB, 512, 0, stream>>>(image, cmap, v_i, out);
}

// Round 12
// 95.151 us; speedup vs baseline: 1.2073x; 1.0062x over previous
//
#include <hip/hip_runtime.h>
#include <hip/hip_fp16.h>

// DifferentiableRGBtoVel: image (4,3,512,512) fp32, cmap (256,3) fp32, v_i (256) fp32
// out velocities (4,512,512) fp32.
//
// v15 (= v11 + LDS-read software pipelining + VGPR headroom):
// logit'_k = 14 - K2*|c_k - p|^2 in exp2 units (bias cancels in softmax ratio).
// Dual-MFMA path (verified since v8b, absmax 0.00390625):
//   MFMA #1 bf16 (3-way splits, 24-slot scheme) -> logits; lane l holds 4
//   logits of pixel (l&15); exp2 -> v_cvt_pkrtz f16; MFMA #2 f16 vs Bv
//   (col0=1, col1=v_k permuted) accumulates s and s*v on the matrix pipe.
//   80B sA stride (conflict-free); rcp epilogue.
//
// v14 post-mortem: VGPR_Count 40 under launch_bounds(512,8) (cap 64) means the
// unrolled u-loop cannot hoist next-u LDS reads (~100cy lgkmcnt each) nor
// overlap exp chains across iterations -> per-u latency tails = the ~15us idle.
// v15: (a) launch_bounds(512,6): VGPR cap ~85, matches the LDS-implied 3
// blocks/CU (45056B) instead of fighting for 4; (b) explicit rotate-prefetch of
// ca/cb/bv one u ahead. Math bit-identical to v11.
//
// Refuted structural variants (kept for the record): v12 persistent blocks
// (neutral), v13 barrier-free wave-private staging (regression: spills).

typedef __attribute__((ext_vector_type(8))) short short8;     // 8 bf16
typedef __attribute__((ext_vector_type(8))) _Float16 f16x8;   // 8 f16
typedef __attribute__((ext_vector_type(4))) float f32x4;

#define HWSZ 262144              // 512*512
#define NPIX 1048576             // 4*512*512
#define K2F  144.2695040888963f  // 1/(0.01*ln2)
#define BIASF 14.0f              // logit bias (cancels in ratio)
#define PXB  256                 // pixels per block

// round f32 -> bf16 bits (RNE); residual (exact in fp32) returned via *resid
static __device__ __forceinline__ unsigned f2bf(float x, float* resid) {
  unsigned u = __builtin_bit_cast(unsigned, x);
  unsigned r = (u + 0x7fffu + ((u >> 16) & 1u)) >> 16;
  if (resid) *resid = x - __builtin_bit_cast(float, r << 16);
  return r;
}
static __device__ __forceinline__ unsigned bfp(unsigned lo, unsigned hi) {
  return (lo & 0xffffu) | (hi << 16);
}
// pack two f32 -> one dword of two RTZ f16 (v_cvt_pkrtz_f16_f32)
static __device__ __forceinline__ unsigned pkrtz(float a, float b) {
  return __builtin_bit_cast(unsigned, __builtin_amdgcn_cvt_pkrtz(a, b));
}

__global__ __launch_bounds__(512, 6) void rgb2vel_main(
    const float* __restrict__ img, const float* __restrict__ cmap,
    const float* __restrict__ vv, float* __restrict__ out) {
  __shared__ __align__(16) int4 sA4[PXB * 5];  // pixel B-frag rows, 80B stride: 20K
  __shared__ __align__(16) int4 sB4[1024];     // color A-frag table: 16K
  __shared__ __align__(16) int4 sBv4[512];     // reduction Bv table: 8K
  const int tid = threadIdx.x;
  const int lane = tid & 63;
  const int warp = tid >> 6;   // 0..7
  const int c = lane & 15;     // pixel-in-tile (D1 col / D2 row-group owner)
  const int g = lane >> 4;     // k-chunk index
  const int pb0 = blockIdx.x * PXB;

  if (tid < 256) {
    // ---- color A-frag table (one color per thread) ----
    int k = tid;
    float c0 = cmap[k * 3 + 0], c1 = cmap[k * 3 + 1], c2 = cmap[k * 3 + 2];
    float cc[3] = {c0, c1, c2};
    unsigned H[3], M[3], L[3];
    float r;
#pragma unroll
    for (int ch = 0; ch < 3; ++ch) {          // 3-way split of 2K2*c
      float x = 2.0f * K2F * cc[ch];
      H[ch] = f2bf(x, &r);
      M[ch] = f2bf(r, &r);
      L[ch] = f2bf(r, nullptr);
    }
    float mcc = BIASF - K2F * (c0 * c0 + c1 * c1 + c2 * c2);
    unsigned mh = f2bf(mcc, &r);
    unsigned mm = f2bf(r, &r);
    unsigned ml = f2bf(r, nullptr);
    const unsigned N1 = 0xBF80u;  // -1.0 bf16
    unsigned d[16];
    d[0] = bfp(H[0], H[1]); d[1] = bfp(H[2], H[0]); d[2] = bfp(H[1], H[2]);
    d[3] = bfp(M[0], M[1]); d[4] = bfp(M[2], L[0]); d[5] = bfp(L[1], L[2]);
    d[6] = bfp(M[0], M[1]); d[7] = bfp(M[2], H[0]); d[8] = bfp(H[1], H[2]);
    d[9] = bfp(mh, mm);     d[10] = bfp(ml, N1);    d[11] = bfp(N1, N1);
    d[12] = d[13] = d[14] = d[15] = 0u;
    int col = k & 15, tt = k >> 4;
#pragma unroll
    for (int g2 = 0; g2 < 4; ++g2)
      sB4[tt * 64 + g2 * 16 + col] =
          make_int4((int)d[4 * g2 + 0], (int)d[4 * g2 + 1],
                    (int)d[4 * g2 + 2], (int)d[4 * g2 + 3]);
  } else {
    // ---- stage 256 pixels as B-frag rows (threads 256..511) ----
    int px = tid - 256;
    int idx = pb0 + px;
    int n = idx >> 18;              // HWSZ = 2^18
    int hw = idx & (HWSZ - 1);
    const float* pbp = img + (size_t)n * 3 * HWSZ + hw;
    float p0 = pbp[0], p1 = pbp[HWSZ], p2 = pbp[2 * HWSZ];
    float pc[3] = {p0, p1, p2};
    unsigned ph[3], pm[3], pl[3];
    float r;
#pragma unroll
    for (int ch = 0; ch < 3; ++ch) {  // 3-way split of p
      ph[ch] = f2bf(pc[ch], &r);
      pm[ch] = f2bf(r, &r);
      pl[ch] = f2bf(r, nullptr);
    }
    float qv = K2F * (p0 * p0 + p1 * p1 + p2 * p2);
    unsigned qh = f2bf(qv, &r);
    unsigned qm = f2bf(r, &r);
    unsigned ql = f2bf(r, nullptr);
    const unsigned ONE = 0x3F80u;
    int4* sb = &sA4[px * 5];
    sb[0] = make_int4((int)bfp(ph[0], ph[1]), (int)bfp(ph[2], pm[0]),
                      (int)bfp(pm[1], pm[2]), (int)bfp(ph[0], ph[1]));
    sb[1] = make_int4((int)bfp(ph[2], ph[0]), (int)bfp(ph[1], ph[2]),
                      (int)bfp(pm[0], pm[1]), (int)bfp(pm[2], pl[0]));
    sb[2] = make_int4((int)bfp(pl[1], pl[2]), (int)bfp(ONE, ONE),
                      (int)bfp(ONE, qh),      (int)bfp(qm, ql));
    sb[3] = make_int4(0, 0, 0, 0);
    // sb[4] is pad, never read
  }

  // ---- reduction Bv table (all 512 threads, one 16B entry each) ----
  {
    int u = tid >> 6, l = tid & 63, cc2 = l & 15, gg = l >> 4;
    int4 q = make_int4(0, 0, 0, 0);
    if (cc2 == 0) {
      q = make_int4(0x3C003C00, 0x3C003C00, 0x3C003C00, 0x3C003C00);  // 1.0h x8
    } else if (cc2 == 1) {
      unsigned hq[4];
#pragma unroll
      for (int jp = 0; jp < 4; ++jp) {
        int j0 = 2 * jp, j1 = 2 * jp + 1;
        int i0 = (2 * u + (j0 >> 2)) * 16 + gg * 4 + (j0 & 3);
        int i1 = (2 * u + (j1 >> 2)) * 16 + gg * 4 + (j1 & 3);
        unsigned h0 = (unsigned)__half_as_ushort(__float2half(vv[i0]));  // RNE
        unsigned h1 = (unsigned)__half_as_ushort(__float2half(vv[i1]));
        hq[jp] = h0 | (h1 << 16);
      }
      q = make_int4((int)hq[0], (int)hq[1], (int)hq[2], (int)hq[3]);
    }
    sBv4[tid] = q;
  }
  __syncthreads();

  // two pixel B-frags per wave: tiles at px warp*16 and 128+warp*16
  short8 pfr0 = __builtin_bit_cast(short8, sA4[(warp * 16 + c) * 5 + g]);
  short8 pfr1 = __builtin_bit_cast(short8, sA4[(128 + warp * 16 + c) * 5 + g]);

  f32x4 accA = {0.f, 0.f, 0.f, 0.f};
  f32x4 accB = {0.f, 0.f, 0.f, 0.f};
  const f32x4 z = {0.f, 0.f, 0.f, 0.f};

  // software-pipelined LDS reads: u+1's ca/cb/bv load before u's exp section
  short8 ca = __builtin_bit_cast(short8, sB4[0 * 64 + lane]);
  short8 cb = __builtin_bit_cast(short8, sB4[1 * 64 + lane]);
  f16x8 bv = __builtin_bit_cast(f16x8, sBv4[0 * 64 + lane]);

#pragma unroll
  for (int u = 0; u < 8; ++u) {
    f32x4 d0a = __builtin_amdgcn_mfma_f32_16x16x32_bf16(ca, pfr0, z, 0, 0, 0);
    f32x4 d1a = __builtin_amdgcn_mfma_f32_16x16x32_bf16(cb, pfr0, z, 0, 0, 0);
    f32x4 d0b = __builtin_amdgcn_mfma_f32_16x16x32_bf16(ca, pfr1, z, 0, 0, 0);
    f32x4 d1b = __builtin_amdgcn_mfma_f32_16x16x32_bf16(cb, pfr1, z, 0, 0, 0);
    short8 nca, ncb;
    f16x8 nbv;
    if (u + 1 < 8) {
      nca = __builtin_bit_cast(short8, sB4[(2 * u + 2) * 64 + lane]);
      ncb = __builtin_bit_cast(short8, sB4[(2 * u + 3) * 64 + lane]);
      nbv = __builtin_bit_cast(f16x8, sBv4[(u + 1) * 64 + lane]);
    }
    union { unsigned w[4]; f16x8 v8; } wa, wb;
    wa.w[0] = pkrtz(__builtin_amdgcn_exp2f(d0a[0]), __builtin_amdgcn_exp2f(d0a[1]));
    wa.w[1] = pkrtz(__builtin_amdgcn_exp2f(d0a[2]), __builtin_amdgcn_exp2f(d0a[3]));
    wa.w[2] = pkrtz(__builtin_amdgcn_exp2f(d1a[0]), __builtin_amdgcn_exp2f(d1a[1]));
    wa.w[3] = pkrtz(__builtin_amdgcn_exp2f(d1a[2]), __builtin_amdgcn_exp2f(d1a[3]));
    wb.w[0] = pkrtz(__builtin_amdgcn_exp2f(d0b[0]), __builtin_amdgcn_exp2f(d0b[1]));
    wb.w[1] = pkrtz(__builtin_amdgcn_exp2f(d0b[2]), __builtin_amdgcn_exp2f(d0b[3]));
    wb.w[2] = pkrtz(__builtin_amdgcn_exp2f(d1b[0]), __builtin_amdgcn_exp2f(d1b[1]));
    wb.w[3] = pkrtz(__builtin_amdgcn_exp2f(d1b[2]), __builtin_amdgcn_exp2f(d1b[3]));
    accA = __builtin_amdgcn_mfma_f32_16x16x32_f16(wa.v8, bv, accA, 0, 0, 0);
    accB = __builtin_amdgcn_mfma_f32_16x16x32_f16(wb.v8, bv, accB, 0, 0, 0);
    if (u + 1 < 8) {
      ca = nca;
      cb = ncb;
      bv = nbv;
    }
  }

  // lane 16g+0 holds s, lane 16g+1 holds s*v for pixel rows g*4+rr (both tiles)
  float a0 = __shfl_xor(accA[0], 1);
  float a1 = __shfl_xor(accA[1], 1);
  float a2 = __shfl_xor(accA[2], 1);
  float a3 = __shfl_xor(accA[3], 1);
  float b0 = __shfl_xor(accB[0], 1);
  float b1 = __shfl_xor(accB[1], 1);
  float b2 = __shfl_xor(accB[2], 1);
  float b3 = __shfl_xor(accB[3], 1);
  if (c == 0) {
    float* oA = out + pb0 + warp * 16 + g * 4;
    oA[0] = a0 * __builtin_amdgcn_rcpf(accA[0]);
    oA[1] = a1 * __builtin_amdgcn_rcpf(accA[1]);
    oA[2] = a2 * __builtin_amdgcn_rcpf(accA[2]);
    oA[3] = a3 * __builtin_amdgcn_rcpf(accA[3]);
    float* oB = out + pb0 + 128 + warp * 16 + g * 4;
    oB[0] = b0 * __builtin_amdgcn_rcpf(accB[0]);
    oB[1] = b1 * __builtin_amdgcn_rcpf(accB[1]);
    oB[2] = b2 * __builtin_amdgcn_rcpf(accB[2]);
    oB[3] = b3 * __builtin_amdgcn_rcpf(accB[3]);
  }
}

extern "C" void kernel_launch(void* const* d_in, const int* in_sizes, int n_in,
                              void* d_out, int out_size, void* d_ws, size_t ws_size,
                              hipStream_t stream) {
  const float* image = (const float*)d_in[0];  // (4,3,512,512)
  const float* cmap  = (const float*)d_in[1];  // (256,3)
  const float* v_i   = (const float*)d_in[2];  // (256,)
  float* out = (float*)d_out;                  // (4,512,512)

  rgb2vel_main<<<NPIX / PXB, 512, 0, stream>>>(image, cmap, v_i, out);
}